// Round 3
// baseline (533.451 us; speedup 1.0000x reference)
//
#include <hip/hip_runtime.h>
#include <math.h>
#include <stdint.h>
#include <stddef.h>

typedef __bf16 bf16;
typedef __bf16 bf16x8 __attribute__((ext_vector_type(8)));
typedef __bf16 bf16x4 __attribute__((ext_vector_type(4)));
typedef __bf16 bf16x2 __attribute__((ext_vector_type(2)));
typedef float  f32x4  __attribute__((ext_vector_type(4)));
typedef float  f32x4v __attribute__((ext_vector_type(4)));

typedef __attribute__((address_space(1))) const void* as1cv;
typedef __attribute__((address_space(3))) void*       as3v;

__device__ __forceinline__ f32x4 mfma16(bf16x8 a, bf16x8 b, f32x4 c) {
  return __builtin_amdgcn_mfma_f32_16x16x32_bf16(a, b, c, 0, 0, 0);
}

__device__ __forceinline__ void gload_lds16(const bf16* g, bf16* l) {
  __builtin_amdgcn_global_load_lds((as1cv)g, (as3v)l, 16, 0, 0);
}

// ---------------------------------------------------------------- fused convert
struct CvtTable {
  const float* s[9];
  bf16* d[9];
  int cum[10];
};

__global__ void cvt_all(CvtTable T, int total4) {
  int i = blockIdx.x * blockDim.x + threadIdx.x;
  int stride = gridDim.x * blockDim.x;
  for (; i < total4; i += stride) {
    int k = 0;
#pragma unroll
    for (int j = 1; j < 9; ++j) k += (i >= T.cum[j]) ? 1 : 0;
    int off = i - T.cum[k];
    f32x4v v = ((const f32x4v*)T.s[k])[off];
    bf16x4 o;
    o[0] = (bf16)v[0]; o[1] = (bf16)v[1]; o[2] = (bf16)v[2]; o[3] = (bf16)v[3];
    ((bf16x4*)T.d[k])[off] = o;
  }
}

// ---------------------------------------------------------------- GEMM core  C = A @ B^T
// 128x128 tile, BK=64, double-buffered LDS, 2-phase pipeline.
__device__ __forceinline__ void gemm_core(
    const bf16* __restrict__ A, int lda,
    const bf16* __restrict__ B, int K,
    float* __restrict__ Cf, bf16* __restrict__ Cb, int ldc,
    const float* __restrict__ bias, int bias_n, int m0, int n0)
{
  __shared__ __align__(16) bf16 Al[2][128 * 64];
  __shared__ __align__(16) bf16 Bl[2][128 * 64];
  const int tid = threadIdx.x;
  const int l = tid & 63;
  const int wid = tid >> 6;
  const int wr = wid >> 1, wc = wid & 1;
  const int lr = l & 15, lg = l >> 4;

  auto STAGE = [&](int b, int k0) {
#pragma unroll
    for (int it = 0; it < 4; ++it) {
      int chunk = it * 256 + tid;
      int row = chunk >> 3;
      int scb = (chunk & 7) ^ (row & 7);
      gload_lds16(A + (size_t)(m0 + row) * lda + k0 + scb * 8, &Al[b][chunk * 8]);
    }
#pragma unroll
    for (int it = 0; it < 4; ++it) {
      int chunk = it * 256 + tid;
      int row = chunk >> 3;
      int scb = (chunk & 7) ^ (row & 7);
      gload_lds16(B + (size_t)(n0 + row) * K + k0 + scb * 8, &Bl[b][chunk * 8]);
    }
  };

  f32x4 z = {0.f, 0.f, 0.f, 0.f};
  f32x4 acc[4][4];
#pragma unroll
  for (int i = 0; i < 4; ++i)
#pragma unroll
    for (int j = 0; j < 4; ++j) acc[i][j] = z;

  STAGE(0, 0);
  __syncthreads();
  int cur = 0;
  for (int k0 = 0; k0 < K; k0 += 64) {
    if (k0 + 64 < K) STAGE(cur ^ 1, k0 + 64);
#pragma unroll
    for (int kk = 0; kk < 2; ++kk) {
      bf16x8 af[4], bfr[4];
#pragma unroll
      for (int i = 0; i < 4; ++i) {
        int row = wr * 64 + i * 16 + lr;
        int cq = kk * 4 + lg;
        af[i] = *(const bf16x8*)(&Al[cur][row * 64 + ((cq ^ (row & 7)) * 8)]);
      }
#pragma unroll
      for (int j = 0; j < 4; ++j) {
        int row = wc * 64 + j * 16 + lr;
        int cq = kk * 4 + lg;
        bfr[j] = *(const bf16x8*)(&Bl[cur][row * 64 + ((cq ^ (row & 7)) * 8)]);
      }
#pragma unroll
      for (int i = 0; i < 4; ++i)
#pragma unroll
        for (int j = 0; j < 4; ++j)
          acc[i][j] = mfma16(af[i], bfr[j], acc[i][j]);
    }
    __syncthreads();
    cur ^= 1;
  }

#pragma unroll
  for (int i = 0; i < 4; ++i)
#pragma unroll
    for (int j = 0; j < 4; ++j)
#pragma unroll
      for (int r = 0; r < 4; ++r) {
        int row = m0 + wr * 64 + i * 16 + lg * 4 + r;
        int col = n0 + wc * 64 + j * 16 + lr;
        float v = acc[i][j][r];
        if (bias != nullptr && col < bias_n) v += bias[col];
        if (Cf != nullptr) Cf[(size_t)row * ldc + col] = v;
        else               Cb[(size_t)row * ldc + col] = (bf16)v;
      }
}

template<bool OUTF32>
__global__ __launch_bounds__(256) void gemm_bt(
    const bf16* __restrict__ A, int lda,
    const bf16* __restrict__ B, int K,
    float* __restrict__ Cf, bf16* __restrict__ Cb, int ldc,
    const float* __restrict__ bias, int bias_n)
{
  gemm_core(A, lda, B, K, OUTF32 ? Cf : nullptr, Cb, ldc, bias, bias_n,
            blockIdx.y * 128, blockIdx.x * 128);
}

// Two independent GEMMs in one launch (G2: nbx0 x 16 blocks, then G3).
__global__ __launch_bounds__(256) void gemm_bt_dual(
    const bf16* __restrict__ A0, int lda0, const bf16* __restrict__ B0, int K0,
    bf16* __restrict__ C0, int ldc0, int nbx0,
    const bf16* __restrict__ A1, int lda1, const bf16* __restrict__ B1, int K1,
    bf16* __restrict__ C1, int ldc1, int nbx1)
{
  int bid = blockIdx.x;
  if (bid < nbx0 * 16) {
    gemm_core(A0, lda0, B0, K0, nullptr, C0, ldc0, nullptr, 0,
              (bid / nbx0) * 128, (bid % nbx0) * 128);
  } else {
    bid -= nbx0 * 16;
    gemm_core(A1, lda1, B1, K1, nullptr, C1, ldc1, nullptr, 0,
              (bid / nbx1) * 128, (bid % nbx1) * 128);
  }
}

// ---------------------------------------------------------------- RoPE + V-transpose (fused)
__global__ void rope_tv(const bf16* __restrict__ QA, const bf16* __restrict__ c_all,
                        const float* __restrict__ cosb, const float* __restrict__ sinb,
                        bf16* __restrict__ Qr, bf16* __restrict__ Kr,
                        const bf16* __restrict__ KV, bf16* __restrict__ Vt)
{
  int bid = blockIdx.x;
  if (bid < 2048) {
    int t = bid;
    for (int idx = threadIdx.x; idx < 544; idx += 256) {
      if (idx < 512) {
        int h = idx >> 5, p = idx & 31;
        float x1 = (float)QA[(size_t)t * 3072 + 2048 + h * 64 + p];
        float x2 = (float)QA[(size_t)t * 3072 + 2048 + h * 64 + 32 + p];
        float c = cosb[t * 32 + p], s = sinb[t * 32 + p];
        Qr[(size_t)t * 1024 + h * 64 + p]      = (bf16)( x1 * c + x2 * s);
        Qr[(size_t)t * 1024 + h * 64 + 32 + p] = (bf16)(-x1 * s + x2 * c);
      } else {
        int p = idx - 512;
        float x1 = (float)c_all[(size_t)t * 2176 + 2048 + p];
        float x2 = (float)c_all[(size_t)t * 2176 + 2048 + 32 + p];
        float c = cosb[t * 32 + p], s = sinb[t * 32 + p];
        Kr[(size_t)t * 64 + p]      = (bf16)( x1 * c + x2 * s);
        Kr[(size_t)t * 64 + 32 + p] = (bf16)(-x1 * s + x2 * c);
      }
    }
  } else {
    __shared__ bf16 tile[32][33];
    int tb = bid - 2048;
    int t0 = (tb & 63) * 32, c0 = (tb >> 6) * 32;
    int tx = threadIdx.x & 31, ty = threadIdx.x >> 5;
#pragma unroll
    for (int r = 0; r < 4; ++r)
      tile[ty + r * 8][tx] = KV[(size_t)(t0 + ty + r * 8) * 4096 + 2048 + c0 + tx];
    __syncthreads();
#pragma unroll
    for (int r = 0; r < 4; ++r)
      Vt[(size_t)(c0 + ty + r * 8) * 2048 + t0 + tx] = tile[tx][ty + r * 8];
  }
}

// ---------------------------------------------------------------- flash attention
// Swapped-operand form, no barriers, direct L2 reads.
// 4 waves/block, 16 q-rows/wave. Per 32-key step:
//   S^T = mfma(K_frag, Q_frag)  -> lane owns scores for q = q0 + (lane&15)
//   softmax: 2+2 shfl_xor total; alpha/inv are lane-scalar (O^T layout matches)
//   P^T through 1.25KB/wave LDS; O^T += mfma(Vt_frag, P_frag)
__global__ __launch_bounds__(256) void attn_kernel(
    const bf16* __restrict__ QA,  // 2048 x 3072
    const bf16* __restrict__ Qr,  // 2048 x 1024
    const bf16* __restrict__ KV,  // 2048 x 4096 ([Kfull|Vfull])
    const bf16* __restrict__ Kr,  // 2048 x 64
    const bf16* __restrict__ Vt,  // 2048(c) x 2048(t)
    bf16* __restrict__ heads)     // 2048 x 2048
{
  const int l = threadIdx.x & 63;
  const int wid = threadIdx.x >> 6;
  const int lr = l & 15, lg = l >> 4;
  __shared__ __align__(16) bf16 Pl[4][16][40];   // padded rows (80B)

  // XCD clustering: 2 heads/XCD; longest q-tiles first.
  const int wg = blockIdx.x;
  const int xcd = wg & 7, inx = wg >> 3;
  const int h = xcd * 2 + (inx >> 5);
  const int qb = 31 - (inx & 31);
  const int q0 = qb * 64 + wid * 16;
  const int q = q0 + lr;                // this lane's q-row (S^T col, O^T col)

  const float scale = 0.041666666666666664f;  // 1/sqrt(576)
  f32x4 z = {0.f, 0.f, 0.f, 0.f};

  // Q B-fragments (col = q, k-dim = d), d = 192 over 6 slices of 32
  bf16x8 aq[6];
#pragma unroll
  for (int kc = 0; kc < 4; ++kc)
    aq[kc] = *(const bf16x8*)&QA[(size_t)q * 3072 + h * 128 + kc * 32 + lg * 8];
#pragma unroll
  for (int kc = 4; kc < 6; ++kc)
    aq[kc] = *(const bf16x8*)&Qr[(size_t)q * 1024 + h * 64 + (kc - 4) * 32 + lg * 8];

  float m_run = -1e30f, l_run = 0.f;
  f32x4 acc[8];
#pragma unroll
  for (int c = 0; c < 8; ++c) acc[c] = z;

  const int nS = (q0 + 47) >> 5;
  for (int st = 0; st < nS; ++st) {
    const int s0 = st * 32;
    // QK^T (swapped): A = K rows (16 keys), B = Q
    f32x4 sc[2];
    sc[0] = z; sc[1] = z;
#pragma unroll
    for (int t = 0; t < 2; ++t) {
      const size_t krow = (size_t)(s0 + t * 16 + lr);
#pragma unroll
      for (int kc = 0; kc < 4; ++kc) {
        bf16x8 ka = *(const bf16x8*)&KV[krow * 4096 + h * 128 + kc * 32 + lg * 8];
        sc[t] = mfma16(ka, aq[kc], sc[t]);
      }
#pragma unroll
      for (int kc = 4; kc < 6; ++kc) {
        bf16x8 ka = *(const bf16x8*)&Kr[krow * 64 + (kc - 4) * 32 + lg * 8];
        sc[t] = mfma16(ka, aq[kc], sc[t]);
      }
    }
    // lane holds S^T[k = s0 + t*16 + lg*4 + r][q]
    float pv[2][4];
    float mx = -1e30f;
#pragma unroll
    for (int t = 0; t < 2; ++t)
#pragma unroll
      for (int r = 0; r < 4; ++r) {
        int k = s0 + t * 16 + lg * 4 + r;
        float v = sc[t][r] * scale;
        if (k > q) v = -1e30f;
        pv[t][r] = v;
        mx = fmaxf(mx, v);
      }
    mx = fmaxf(mx, __shfl_xor(mx, 16, 64));
    mx = fmaxf(mx, __shfl_xor(mx, 32, 64));
    float mnew = fmaxf(m_run, mx);
    float alpha = __expf(m_run - mnew);
    float sum = 0.f;
#pragma unroll
    for (int t = 0; t < 2; ++t)
#pragma unroll
      for (int r = 0; r < 4; ++r) {
        float e = __expf(pv[t][r] - mnew);
        pv[t][r] = e;
        sum += e;
      }
    sum += __shfl_xor(sum, 16, 64);
    sum += __shfl_xor(sum, 32, 64);
    l_run = l_run * alpha + sum;
    m_run = mnew;
#pragma unroll
    for (int c = 0; c < 8; ++c)
#pragma unroll
      for (int r = 0; r < 4; ++r) acc[c][r] *= alpha;
    // P^T -> per-wave LDS: P_lds[q-row lr][k_local], k_local = t*16 + lg*4 + r
#pragma unroll
    for (int t = 0; t < 2; ++t)
#pragma unroll
      for (int hf = 0; hf < 2; ++hf) {
        bf16x2 w;
        w[0] = (bf16)pv[t][2 * hf];
        w[1] = (bf16)pv[t][2 * hf + 1];
        *(bf16x2*)&Pl[wid][lr][t * 16 + lg * 4 + 2 * hf] = w;
      }
    bf16x8 pa = *(const bf16x8*)&Pl[wid][lr][lg * 8];   // P^T[k=lg*8..][q]
    // PV (O^T): A = Vt rows (c), B = P^T
#pragma unroll
    for (int c = 0; c < 8; ++c) {
      bf16x8 va = *(const bf16x8*)&Vt[(size_t)(h * 128 + c * 16 + lr) * 2048 + s0 + lg * 8];
      acc[c] = mfma16(va, pa, acc[c]);
    }
  }

  const float inv = 1.f / l_run;
#pragma unroll
  for (int c = 0; c < 8; ++c) {
    bf16x4 o;
#pragma unroll
    for (int r = 0; r < 4; ++r) o[r] = (bf16)(acc[c][r] * inv);
    *(bf16x4*)&heads[(size_t)q * 2048 + h * 128 + c * 16 + lg * 4] = o;
  }
}

// ---------------------------------------------------------------- launch
extern "C" void kernel_launch(void* const* d_in, const int* in_sizes, int n_in,
                              void* d_out, int out_size, void* d_ws, size_t ws_size,
                              hipStream_t stream) {
  (void)in_sizes; (void)n_in; (void)out_size; (void)ws_size;
  const float* x      = (const float*)d_in[0];
  const float* cosp   = (const float*)d_in[1];
  const float* sinp   = (const float*)d_in[2];
  const float* Wq_d   = (const float*)d_in[3];
  const float* Wq_d_b = (const float*)d_in[4];
  const float* Wkv_d  = (const float*)d_in[5];
  const float* Wq_u   = (const float*)d_in[6];
  const float* Wk_u   = (const float*)d_in[7];
  const float* Wv_u   = (const float*)d_in[8];
  const float* W_qr   = (const float*)d_in[9];
  const float* W_kr   = (const float*)d_in[10];
  const float* W_out  = (const float*)d_in[11];

  char* ws = (char*)d_ws;
  size_t off = 0;
  auto alloc = [&](size_t bytes) {
    char* p = ws + off;
    off += (bytes + 255) & ~(size_t)255;
    return p;
  };
  bf16* xb    = (bf16*)alloc((size_t)2048 * 2048 * 2);  // reused as Vt after G1
  bf16* Wcat  = (bf16*)alloc((size_t)2176 * 2048 * 2);
  bf16* c_all = (bf16*)alloc((size_t)2048 * 2176 * 2);
  bf16* Wqu   = (bf16*)alloc((size_t)3072 * 1536 * 2);  // reused as heads
  bf16* QA    = (bf16*)alloc((size_t)2048 * 3072 * 2);
  bf16* Wkvu  = (bf16*)alloc((size_t)4096 * 512 * 2);
  bf16* KV    = (bf16*)alloc((size_t)2048 * 4096 * 2);
  bf16* Qr    = (bf16*)alloc((size_t)2048 * 1024 * 2);
  bf16* Kr    = (bf16*)alloc((size_t)2048 * 64 * 2);
  bf16* Wout  = (bf16*)alloc((size_t)2048 * 2048 * 2);
  bf16* Vt    = xb;
  bf16* heads = Wqu;

  CvtTable T;
  const float* srcs[9] = { x, Wq_d, Wkv_d, W_kr, Wq_u, W_qr, Wk_u, Wv_u, W_out };
  bf16* dsts[9] = { xb, Wcat, Wcat + (size_t)1536 * 2048, Wcat + (size_t)2048 * 2048,
                    Wqu, Wqu + (size_t)2048 * 1536, Wkvu, Wkvu + (size_t)2048 * 512, Wout };
  size_t ns[9] = { (size_t)2048 * 2048, (size_t)1536 * 2048, (size_t)512 * 2048,
                   (size_t)64 * 2048, (size_t)2048 * 1536, (size_t)1024 * 1536,
                   (size_t)2048 * 512, (size_t)2048 * 512, (size_t)2048 * 2048 };
  int cum = 0;
  for (int i = 0; i < 9; ++i) {
    T.s[i] = srcs[i]; T.d[i] = dsts[i]; T.cum[i] = cum;
    cum += (int)(ns[i] / 4);
  }
  T.cum[9] = cum;
  cvt_all<<<2048, 256, 0, stream>>>(T, cum);

  // G1: c_all = x @ [Wq_d;Wkv_d;W_kr]^T + bias(cols<1536)
  gemm_bt<false><<<dim3(17, 16), 256, 0, stream>>>(xb, 2048, Wcat, 2048,
                                                   nullptr, c_all, 2176, Wq_d_b, 1536);
  // G2 + G3 fused launch: QA = cq @ [Wq_u;W_qr]^T ; KV = ckv @ [Wk_u;Wv_u]^T
  gemm_bt_dual<<<24 * 16 + 32 * 16, 256, 0, stream>>>(
      c_all, 2176, Wqu, 1536, QA, 3072, 24,
      c_all + 1536, 2176, Wkvu, 512, KV, 4096, 32);
  // RoPE + V transpose fused
  rope_tv<<<2048 + 4096, 256, 0, stream>>>(QA, c_all, cosp, sinp, Qr, Kr, KV, Vt);
  attn_kernel<<<512, 256, 0, stream>>>(QA, Qr, KV, Kr, Vt, heads);
  // G4: out = heads @ W_out^T  (f32 to d_out)
  gemm_bt<true><<<dim3(16, 16), 256, 0, stream>>>(heads, 2048, Wout, 2048,
                                                  (float*)d_out, nullptr, 2048, nullptr, 0);
}

// Round 4
// 340.585 us; speedup vs baseline: 1.5663x; 1.5663x over previous
//
#include <hip/hip_runtime.h>
#include <math.h>
#include <stdint.h>
#include <stddef.h>

typedef __bf16 bf16;
typedef __bf16 bf16x8 __attribute__((ext_vector_type(8)));
typedef __bf16 bf16x4 __attribute__((ext_vector_type(4)));
typedef __bf16 bf16x2 __attribute__((ext_vector_type(2)));
typedef float  f32x4  __attribute__((ext_vector_type(4)));
typedef float  f32x4v __attribute__((ext_vector_type(4)));

typedef __attribute__((address_space(1))) const void* as1cv;
typedef __attribute__((address_space(3))) void*       as3v;

__device__ __forceinline__ f32x4 mfma16(bf16x8 a, bf16x8 b, f32x4 c) {
  return __builtin_amdgcn_mfma_f32_16x16x32_bf16(a, b, c, 0, 0, 0);
}

__device__ __forceinline__ void gload_lds16(const bf16* g, bf16* l) {
  __builtin_amdgcn_global_load_lds((as1cv)g, (as3v)l, 16, 0, 0);
}

// ---------------------------------------------------------------- fused convert
struct CvtTable {
  const float* s[9];
  bf16* d[9];
  int cum[10];
};

__global__ void cvt_all(CvtTable T, int total4) {
  int i = blockIdx.x * blockDim.x + threadIdx.x;
  int stride = gridDim.x * blockDim.x;
  for (; i < total4; i += stride) {
    int k = 0;
#pragma unroll
    for (int j = 1; j < 9; ++j) k += (i >= T.cum[j]) ? 1 : 0;
    int off = i - T.cum[k];
    f32x4v v = ((const f32x4v*)T.s[k])[off];
    bf16x4 o;
    o[0] = (bf16)v[0]; o[1] = (bf16)v[1]; o[2] = (bf16)v[2]; o[3] = (bf16)v[3];
    ((bf16x4*)T.d[k])[off] = o;
  }
}

// ---------------------------------------------------------------- GEMM core  C = A @ B^T
// 128x128 tile, BK=64, double-buffered LDS, 2-phase pipeline.
__device__ __forceinline__ void gemm_core(
    const bf16* __restrict__ A, int lda,
    const bf16* __restrict__ B, int K,
    float* __restrict__ Cf, bf16* __restrict__ Cb, int ldc,
    const float* __restrict__ bias, int bias_n, int m0, int n0)
{
  __shared__ __align__(16) bf16 Al[2][128 * 64];
  __shared__ __align__(16) bf16 Bl[2][128 * 64];
  const int tid = threadIdx.x;
  const int l = tid & 63;
  const int wid = tid >> 6;
  const int wr = wid >> 1, wc = wid & 1;
  const int lr = l & 15, lg = l >> 4;

  auto STAGE = [&](int b, int k0) {
#pragma unroll
    for (int it = 0; it < 4; ++it) {
      int chunk = it * 256 + tid;
      int row = chunk >> 3;
      int scb = (chunk & 7) ^ (row & 7);
      gload_lds16(A + (size_t)(m0 + row) * lda + k0 + scb * 8, &Al[b][chunk * 8]);
    }
#pragma unroll
    for (int it = 0; it < 4; ++it) {
      int chunk = it * 256 + tid;
      int row = chunk >> 3;
      int scb = (chunk & 7) ^ (row & 7);
      gload_lds16(B + (size_t)(n0 + row) * K + k0 + scb * 8, &Bl[b][chunk * 8]);
    }
  };

  f32x4 z = {0.f, 0.f, 0.f, 0.f};
  f32x4 acc[4][4];
#pragma unroll
  for (int i = 0; i < 4; ++i)
#pragma unroll
    for (int j = 0; j < 4; ++j) acc[i][j] = z;

  STAGE(0, 0);
  __syncthreads();
  int cur = 0;
  for (int k0 = 0; k0 < K; k0 += 64) {
    if (k0 + 64 < K) STAGE(cur ^ 1, k0 + 64);
#pragma unroll
    for (int kk = 0; kk < 2; ++kk) {
      bf16x8 af[4], bfr[4];
#pragma unroll
      for (int i = 0; i < 4; ++i) {
        int row = wr * 64 + i * 16 + lr;
        int cq = kk * 4 + lg;
        af[i] = *(const bf16x8*)(&Al[cur][row * 64 + ((cq ^ (row & 7)) * 8)]);
      }
#pragma unroll
      for (int j = 0; j < 4; ++j) {
        int row = wc * 64 + j * 16 + lr;
        int cq = kk * 4 + lg;
        bfr[j] = *(const bf16x8*)(&Bl[cur][row * 64 + ((cq ^ (row & 7)) * 8)]);
      }
#pragma unroll
      for (int i = 0; i < 4; ++i)
#pragma unroll
        for (int j = 0; j < 4; ++j)
          acc[i][j] = mfma16(af[i], bfr[j], acc[i][j]);
    }
    __syncthreads();
    cur ^= 1;
  }

#pragma unroll
  for (int i = 0; i < 4; ++i)
#pragma unroll
    for (int j = 0; j < 4; ++j)
#pragma unroll
      for (int r = 0; r < 4; ++r) {
        int row = m0 + wr * 64 + i * 16 + lg * 4 + r;
        int col = n0 + wc * 64 + j * 16 + lr;
        float v = acc[i][j][r];
        if (bias != nullptr && col < bias_n) v += bias[col];
        if (Cf != nullptr) Cf[(size_t)row * ldc + col] = v;
        else               Cb[(size_t)row * ldc + col] = (bf16)v;
      }
}

template<bool OUTF32>
__global__ __launch_bounds__(256) void gemm_bt(
    const bf16* __restrict__ A, int lda,
    const bf16* __restrict__ B, int K,
    float* __restrict__ Cf, bf16* __restrict__ Cb, int ldc,
    const float* __restrict__ bias, int bias_n)
{
  gemm_core(A, lda, B, K, OUTF32 ? Cf : nullptr, Cb, ldc, bias, bias_n,
            blockIdx.y * 128, blockIdx.x * 128);
}

// Two independent GEMMs in one launch.
__global__ __launch_bounds__(256) void gemm_bt_dual(
    const bf16* __restrict__ A0, int lda0, const bf16* __restrict__ B0, int K0,
    bf16* __restrict__ C0, int ldc0, int nbx0,
    const bf16* __restrict__ A1, int lda1, const bf16* __restrict__ B1, int K1,
    bf16* __restrict__ C1, int ldc1, int nbx1)
{
  int bid = blockIdx.x;
  if (bid < nbx0 * 16) {
    gemm_core(A0, lda0, B0, K0, nullptr, C0, ldc0, nullptr, 0,
              (bid / nbx0) * 128, (bid % nbx0) * 128);
  } else {
    bid -= nbx0 * 16;
    gemm_core(A1, lda1, B1, K1, nullptr, C1, ldc1, nullptr, 0,
              (bid / nbx1) * 128, (bid % nbx1) * 128);
  }
}

// ---------------------------------------------------------------- RoPE + V-transpose (fused)
__global__ void rope_tv(const bf16* __restrict__ QA, const bf16* __restrict__ c_all,
                        const float* __restrict__ cosb, const float* __restrict__ sinb,
                        bf16* __restrict__ Qr, bf16* __restrict__ Kr,
                        const bf16* __restrict__ KV, bf16* __restrict__ Vt)
{
  int bid = blockIdx.x;
  if (bid < 2048) {
    int t = bid;
    for (int idx = threadIdx.x; idx < 544; idx += 256) {
      if (idx < 512) {
        int h = idx >> 5, p = idx & 31;
        float x1 = (float)QA[(size_t)t * 3072 + 2048 + h * 64 + p];
        float x2 = (float)QA[(size_t)t * 3072 + 2048 + h * 64 + 32 + p];
        float c = cosb[t * 32 + p], s = sinb[t * 32 + p];
        Qr[(size_t)t * 1024 + h * 64 + p]      = (bf16)( x1 * c + x2 * s);
        Qr[(size_t)t * 1024 + h * 64 + 32 + p] = (bf16)(-x1 * s + x2 * c);
      } else {
        int p = idx - 512;
        float x1 = (float)c_all[(size_t)t * 2176 + 2048 + p];
        float x2 = (float)c_all[(size_t)t * 2176 + 2048 + 32 + p];
        float c = cosb[t * 32 + p], s = sinb[t * 32 + p];
        Kr[(size_t)t * 64 + p]      = (bf16)( x1 * c + x2 * s);
        Kr[(size_t)t * 64 + 32 + p] = (bf16)(-x1 * s + x2 * c);
      }
    }
  } else {
    __shared__ bf16 tile[32][33];
    int tb = bid - 2048;
    int t0 = (tb & 63) * 32, c0 = (tb >> 6) * 32;
    int tx = threadIdx.x & 31, ty = threadIdx.x >> 5;
#pragma unroll
    for (int r = 0; r < 4; ++r)
      tile[ty + r * 8][tx] = KV[(size_t)(t0 + ty + r * 8) * 4096 + 2048 + c0 + tx];
    __syncthreads();
#pragma unroll
    for (int r = 0; r < 4; ++r)
      Vt[(size_t)(c0 + ty + r * 8) * 2048 + t0 + tx] = tile[tx][ty + r * 8];
  }
}

// ---------------------------------------------------------------- flash attention
// Hybrid: LDS-staged K/Kr/V (double-buffered, XOR-swizzled, pre-swizzled
// global_load_lds source) + swapped-operand compute:
//   S^T = mfma(K_frag, Q_frag): lane owns scores for q = q0 + (lane&15)
//   softmax: 2+2 shfl_xor total; alpha/inv lane-scalar
//   P^T via 1.25KB/wave LDS; O^T += mfma(Vt_frag, P^T_frag)
__global__ __launch_bounds__(256) void attn_kernel(
    const bf16* __restrict__ QA,  // 2048 x 3072
    const bf16* __restrict__ Qr,  // 2048 x 1024
    const bf16* __restrict__ KV,  // 2048 x 4096 ([Kfull|Vfull])
    const bf16* __restrict__ Kr,  // 2048 x 64
    const bf16* __restrict__ Vt,  // 2048(c) x 2048(t)
    bf16* __restrict__ heads)     // 2048 x 2048
{
  __shared__ __align__(16) bf16 Kl[2][32 * 128];
  __shared__ __align__(16) bf16 Krl[2][32 * 64];
  __shared__ __align__(16) bf16 Vl[2][128 * 32];
  __shared__ __align__(16) bf16 Pl[4][16][40];

  const int tid = threadIdx.x;
  const int l = tid & 63;
  const int wid = tid >> 6;
  const int lr = l & 15, lg = l >> 4;

  // XCD clustering: 2 heads/XCD. First half of blocks qb descending, second
  // half ascending -> co-resident pairs (wg, wg+256) are long+short.
  const int wg = blockIdx.x;
  const int xcd = wg & 7, inx = wg >> 3;
  const int half = inx >> 5, j = inx & 31;
  const int h = xcd * 2 + half;
  const int qb = half ? j : 31 - j;
  const int q0 = qb * 64 + wid * 16;
  const int q = q0 + lr;               // this lane's q-row

  const float scale = 0.041666666666666664f;  // 1/sqrt(576)
  f32x4 z = {0.f, 0.f, 0.f, 0.f};

  auto STAGE = [&](int b, int s0) {
#pragma unroll
    for (int it = 0; it < 2; ++it) {        // Kl: 512 granules (32 rows x 16)
      int ch = it * 256 + tid;
      int r = ch >> 4, p = ch & 15;
      int cb = (p & 8) | ((p & 7) ^ (r & 7));
      gload_lds16(&KV[(size_t)(s0 + r) * 4096 + h * 128 + cb * 8], &Kl[b][ch * 8]);
    }
    {                                       // Krl: 256 granules (32 rows x 8)
      int ch = tid;
      int r = ch >> 3, p = ch & 7;
      int cb = p ^ (r & 7);
      gload_lds16(&Kr[(size_t)(s0 + r) * 64 + cb * 8], &Krl[b][ch * 8]);
    }
#pragma unroll
    for (int it = 0; it < 2; ++it) {        // Vl: 512 granules (128 rows x 4)
      int ch = it * 256 + tid;
      int r = ch >> 2, p = ch & 3;
      int cb = p ^ ((r >> 1) & 3);
      gload_lds16(&Vt[(size_t)(h * 128 + r) * 2048 + s0 + cb * 8], &Vl[b][ch * 8]);
    }
  };

  // Q B-fragments (col = q), d = 192 over 6 slices of 32 (hoisted, registers)
  bf16x8 aq[6];
#pragma unroll
  for (int kc = 0; kc < 4; ++kc)
    aq[kc] = *(const bf16x8*)&QA[(size_t)q * 3072 + h * 128 + kc * 32 + lg * 8];
#pragma unroll
  for (int kc = 4; kc < 6; ++kc)
    aq[kc] = *(const bf16x8*)&Qr[(size_t)q * 1024 + h * 64 + (kc - 4) * 32 + lg * 8];

  float m_run = -1e30f, l_run = 0.f;
  f32x4 acc[8];
#pragma unroll
  for (int c = 0; c < 8; ++c) acc[c] = z;

  const int nIter = 2 * qb + 2;
  STAGE(0, 0);
  __syncthreads();
  int cur = 0;
  for (int st = 0; st < nIter; ++st) {
    const int s0 = st * 32;
    if (st + 1 < nIter) STAGE(cur ^ 1, s0 + 32);
    if (s0 <= q0 + 15) {                    // wave-uniform activity mask
      // QK^T (swapped): A = K rows from LDS, B = Q registers
      f32x4 sc[2];
      sc[0] = z; sc[1] = z;
#pragma unroll
      for (int t = 0; t < 2; ++t) {
        const int rr = t * 16 + lr;
#pragma unroll
        for (int kc = 0; kc < 4; ++kc) {
          int g = kc * 4 + lg;
          bf16x8 ka = *(const bf16x8*)&Kl[cur][rr * 128 + (((g & 8) | ((g & 7) ^ (rr & 7))) * 8)];
          sc[t] = mfma16(ka, aq[kc], sc[t]);
        }
#pragma unroll
        for (int kc = 4; kc < 6; ++kc) {
          int g = (kc - 4) * 4 + lg;
          bf16x8 ka = *(const bf16x8*)&Krl[cur][rr * 64 + ((g ^ (rr & 7)) * 8)];
          sc[t] = mfma16(ka, aq[kc], sc[t]);
        }
      }
      // lane holds S^T[k = s0 + t*16 + lg*4 + r][q]
      float pv[2][4];
      float mx = -1e30f;
#pragma unroll
      for (int t = 0; t < 2; ++t)
#pragma unroll
        for (int r = 0; r < 4; ++r) {
          int k = s0 + t * 16 + lg * 4 + r;
          float v = sc[t][r] * scale;
          if (k > q) v = -1e30f;
          pv[t][r] = v;
          mx = fmaxf(mx, v);
        }
      mx = fmaxf(mx, __shfl_xor(mx, 16, 64));
      mx = fmaxf(mx, __shfl_xor(mx, 32, 64));
      float mnew = fmaxf(m_run, mx);
      float alpha = __expf(m_run - mnew);
      float sum = 0.f;
#pragma unroll
      for (int t = 0; t < 2; ++t)
#pragma unroll
        for (int r = 0; r < 4; ++r) {
          float e = __expf(pv[t][r] - mnew);
          pv[t][r] = e;
          sum += e;
        }
      sum += __shfl_xor(sum, 16, 64);
      sum += __shfl_xor(sum, 32, 64);
      l_run = l_run * alpha + sum;
      m_run = mnew;
#pragma unroll
      for (int c = 0; c < 8; ++c)
#pragma unroll
        for (int r = 0; r < 4; ++r) acc[c][r] *= alpha;
      // P^T -> per-wave LDS: Pl[q-local lr][k_local]
#pragma unroll
      for (int t = 0; t < 2; ++t)
#pragma unroll
        for (int hf = 0; hf < 2; ++hf) {
          bf16x2 w;
          w[0] = (bf16)pv[t][2 * hf];
          w[1] = (bf16)pv[t][2 * hf + 1];
          *(bf16x2*)&Pl[wid][lr][t * 16 + lg * 4 + 2 * hf] = w;
        }
      bf16x8 pa = *(const bf16x8*)&Pl[wid][lr][lg * 8];
      // PV (O^T): A = Vt rows from LDS, B = P^T
#pragma unroll
      for (int c = 0; c < 8; ++c) {
        int rv = c * 16 + lr;
        bf16x8 va = *(const bf16x8*)&Vl[cur][rv * 32 + ((lg ^ ((rv >> 1) & 3)) * 8)];
        acc[c] = mfma16(va, pa, acc[c]);
      }
    }
    __syncthreads();
    cur ^= 1;
  }

  const float inv = 1.f / l_run;
#pragma unroll
  for (int c = 0; c < 8; ++c) {
    bf16x4 o;
#pragma unroll
    for (int r = 0; r < 4; ++r) o[r] = (bf16)(acc[c][r] * inv);
    *(bf16x4*)&heads[(size_t)q * 2048 + h * 128 + c * 16 + lg * 4] = o;
  }
}

// ---------------------------------------------------------------- launch
extern "C" void kernel_launch(void* const* d_in, const int* in_sizes, int n_in,
                              void* d_out, int out_size, void* d_ws, size_t ws_size,
                              hipStream_t stream) {
  (void)in_sizes; (void)n_in; (void)out_size; (void)ws_size;
  const float* x      = (const float*)d_in[0];
  const float* cosp   = (const float*)d_in[1];
  const float* sinp   = (const float*)d_in[2];
  const float* Wq_d   = (const float*)d_in[3];
  const float* Wq_d_b = (const float*)d_in[4];
  const float* Wkv_d  = (const float*)d_in[5];
  const float* Wq_u   = (const float*)d_in[6];
  const float* Wk_u   = (const float*)d_in[7];
  const float* Wv_u   = (const float*)d_in[8];
  const float* W_qr   = (const float*)d_in[9];
  const float* W_kr   = (const float*)d_in[10];
  const float* W_out  = (const float*)d_in[11];

  char* ws = (char*)d_ws;
  size_t off = 0;
  auto alloc = [&](size_t bytes) {
    char* p = ws + off;
    off += (bytes + 255) & ~(size_t)255;
    return p;
  };
  bf16* xb    = (bf16*)alloc((size_t)2048 * 2048 * 2);  // reused as Vt after G1
  bf16* Wcat  = (bf16*)alloc((size_t)2176 * 2048 * 2);
  bf16* c_all = (bf16*)alloc((size_t)2048 * 2176 * 2);
  bf16* Wqu   = (bf16*)alloc((size_t)3072 * 1536 * 2);  // reused as heads
  bf16* QA    = (bf16*)alloc((size_t)2048 * 3072 * 2);
  bf16* Wkvu  = (bf16*)alloc((size_t)4096 * 512 * 2);
  bf16* KV    = (bf16*)alloc((size_t)2048 * 4096 * 2);
  bf16* Qr    = (bf16*)alloc((size_t)2048 * 1024 * 2);
  bf16* Kr    = (bf16*)alloc((size_t)2048 * 64 * 2);
  bf16* Wout  = (bf16*)alloc((size_t)2048 * 2048 * 2);
  bf16* Vt    = xb;
  bf16* heads = Wqu;

  CvtTable T;
  const float* srcs[9] = { x, Wq_d, Wkv_d, W_kr, Wq_u, W_qr, Wk_u, Wv_u, W_out };
  bf16* dsts[9] = { xb, Wcat, Wcat + (size_t)1536 * 2048, Wcat + (size_t)2048 * 2048,
                    Wqu, Wqu + (size_t)2048 * 1536, Wkvu, Wkvu + (size_t)2048 * 512, Wout };
  size_t ns[9] = { (size_t)2048 * 2048, (size_t)1536 * 2048, (size_t)512 * 2048,
                   (size_t)64 * 2048, (size_t)2048 * 1536, (size_t)1024 * 1536,
                   (size_t)2048 * 512, (size_t)2048 * 512, (size_t)2048 * 2048 };
  int cum = 0;
  for (int i = 0; i < 9; ++i) {
    T.s[i] = srcs[i]; T.d[i] = dsts[i]; T.cum[i] = cum;
    cum += (int)(ns[i] / 4);
  }
  T.cum[9] = cum;
  cvt_all<<<2048, 256, 0, stream>>>(T, cum);

  // G1: c_all = x @ [Wq_d;Wkv_d;W_kr]^T + bias(cols<1536)
  gemm_bt<false><<<dim3(17, 16), 256, 0, stream>>>(xb, 2048, Wcat, 2048,
                                                   nullptr, c_all, 2176, Wq_d_b, 1536);
  // G2 + G3 fused launch: QA = cq @ [Wq_u;W_qr]^T ; KV = ckv @ [Wk_u;Wv_u]^T
  gemm_bt_dual<<<24 * 16 + 32 * 16, 256, 0, stream>>>(
      c_all, 2176, Wqu, 1536, QA, 3072, 24,
      c_all + 1536, 2176, Wkvu, 512, KV, 4096, 32);
  // RoPE + V transpose fused
  rope_tv<<<2048 + 4096, 256, 0, stream>>>(QA, c_all, cosp, sinp, Qr, Kr, KV, Vt);
  attn_kernel<<<512, 256, 0, stream>>>(QA, Qr, KV, Kr, Vt, heads);
  // G4: out = heads @ W_out^T  (f32 to d_out)
  gemm_bt<true><<<dim3(16, 16), 256, 0, stream>>>(heads, 2048, Wout, 2048,
                                                  (float*)d_out, nullptr, 2048, nullptr, 0);
}

// Round 5
// 305.847 us; speedup vs baseline: 1.7442x; 1.1136x over previous
//
#include <hip/hip_runtime.h>
#include <math.h>
#include <stdint.h>
#include <stddef.h>

typedef __bf16 bf16;
typedef __bf16 bf16x8 __attribute__((ext_vector_type(8)));
typedef __bf16 bf16x4 __attribute__((ext_vector_type(4)));
typedef __bf16 bf16x2 __attribute__((ext_vector_type(2)));
typedef float  f32x4  __attribute__((ext_vector_type(4)));
typedef float  f32x4v __attribute__((ext_vector_type(4)));

typedef __attribute__((address_space(1))) const void* as1cv;
typedef __attribute__((address_space(3))) void*       as3v;

__device__ __forceinline__ f32x4 mfma16(bf16x8 a, bf16x8 b, f32x4 c) {
  return __builtin_amdgcn_mfma_f32_16x16x32_bf16(a, b, c, 0, 0, 0);
}

__device__ __forceinline__ void gload_lds16(const bf16* g, bf16* l) {
  __builtin_amdgcn_global_load_lds((as1cv)g, (as3v)l, 16, 0, 0);
}

// ---------------------------------------------------------------- fused convert
struct CvtTable {
  const float* s[9];
  bf16* d[9];
  int cum[10];
};

__global__ void cvt_all(CvtTable T, int total4) {
  int i = blockIdx.x * blockDim.x + threadIdx.x;
  int stride = gridDim.x * blockDim.x;
  for (; i < total4; i += stride) {
    int k = 0;
#pragma unroll
    for (int j = 1; j < 9; ++j) k += (i >= T.cum[j]) ? 1 : 0;
    int off = i - T.cum[k];
    f32x4v v = ((const f32x4v*)T.s[k])[off];
    bf16x4 o;
    o[0] = (bf16)v[0]; o[1] = (bf16)v[1]; o[2] = (bf16)v[2]; o[3] = (bf16)v[3];
    ((bf16x4*)T.d[k])[off] = o;
  }
}

// ---------------------------------------------------------------- GEMM core  C = A @ B^T
// 128x128 tile, BK=64, double-buffered LDS, 2-phase pipeline, 8 waves (2x4):
// each wave owns 64x32 output. 2 waves/SIMD inside one block so MFMA and the
// next tile's global_load_lds overlap even at 1 block/CU.
__device__ __forceinline__ void gemm_core(
    const bf16* __restrict__ A, int lda,
    const bf16* __restrict__ B, int K,
    float* __restrict__ Cf, bf16* __restrict__ Cb, int ldc,
    const float* __restrict__ bias, int bias_n, int m0, int n0)
{
  __shared__ __align__(16) bf16 Al[2][128 * 64];
  __shared__ __align__(16) bf16 Bl[2][128 * 64];
  const int tid = threadIdx.x;           // 0..511
  const int l = tid & 63;
  const int wid = tid >> 6;              // 0..7
  const int wr = wid >> 2, wc = wid & 3; // 2 x 4 wave grid
  const int lr = l & 15, lg = l >> 4;

  // staging: 1024 granules of 8 elems per array; thread owns granules tid, tid+512
  const int ch0 = tid, ch1 = tid + 512;
  const int ar0 = ch0 >> 3, ap0 = (ch0 & 7) ^ (ar0 & 7);
  const int ar1 = ch1 >> 3, ap1 = (ch1 & 7) ^ (ar1 & 7);
  const bf16* pA0 = A + (size_t)(m0 + ar0) * lda + ap0 * 8;
  const bf16* pA1 = A + (size_t)(m0 + ar1) * lda + ap1 * 8;
  const bf16* pB0 = B + (size_t)(n0 + ar0) * K + ap0 * 8;
  const bf16* pB1 = B + (size_t)(n0 + ar1) * K + ap1 * 8;
  bf16* dA0[2] = { &Al[0][ch0 * 8], &Al[1][ch0 * 8] };
  bf16* dA1[2] = { &Al[0][ch1 * 8], &Al[1][ch1 * 8] };
  bf16* dB0[2] = { &Bl[0][ch0 * 8], &Bl[1][ch0 * 8] };
  bf16* dB1[2] = { &Bl[0][ch1 * 8], &Bl[1][ch1 * 8] };

  auto STAGE = [&](int b) {
    gload_lds16(pA0, b ? dA0[1] : dA0[0]);
    gload_lds16(pA1, b ? dA1[1] : dA1[0]);
    gload_lds16(pB0, b ? dB0[1] : dB0[0]);
    gload_lds16(pB1, b ? dB1[1] : dB1[0]);
    pA0 += 64; pA1 += 64; pB0 += 64; pB1 += 64;
  };

  f32x4 z = {0.f, 0.f, 0.f, 0.f};
  f32x4 acc[4][2];
#pragma unroll
  for (int i = 0; i < 4; ++i)
#pragma unroll
    for (int j = 0; j < 2; ++j) acc[i][j] = z;

  STAGE(0);
  __syncthreads();
  int cur = 0;
  for (int k0 = 0; k0 < K; k0 += 64) {
    if (k0 + 64 < K) STAGE(cur ^ 1);
#pragma unroll
    for (int kk = 0; kk < 2; ++kk) {
      bf16x8 af[4], bfr[2];
#pragma unroll
      for (int i = 0; i < 4; ++i) {
        int row = wr * 64 + i * 16 + lr;
        int cq = kk * 4 + lg;
        af[i] = *(const bf16x8*)(&Al[cur][row * 64 + ((cq ^ (row & 7)) * 8)]);
      }
#pragma unroll
      for (int j = 0; j < 2; ++j) {
        int row = wc * 32 + j * 16 + lr;
        int cq = kk * 4 + lg;
        bfr[j] = *(const bf16x8*)(&Bl[cur][row * 64 + ((cq ^ (row & 7)) * 8)]);
      }
#pragma unroll
      for (int i = 0; i < 4; ++i)
#pragma unroll
        for (int j = 0; j < 2; ++j)
          acc[i][j] = mfma16(af[i], bfr[j], acc[i][j]);
    }
    __syncthreads();
    cur ^= 1;
  }

#pragma unroll
  for (int i = 0; i < 4; ++i)
#pragma unroll
    for (int j = 0; j < 2; ++j)
#pragma unroll
      for (int r = 0; r < 4; ++r) {
        int row = m0 + wr * 64 + i * 16 + lg * 4 + r;
        int col = n0 + wc * 32 + j * 16 + lr;
        float v = acc[i][j][r];
        if (bias != nullptr && col < bias_n) v += bias[col];
        if (Cf != nullptr) Cf[(size_t)row * ldc + col] = v;
        else               Cb[(size_t)row * ldc + col] = (bf16)v;
      }
}

template<bool OUTF32>
__global__ __launch_bounds__(512) void gemm_bt(
    const bf16* __restrict__ A, int lda,
    const bf16* __restrict__ B, int K,
    float* __restrict__ Cf, bf16* __restrict__ Cb, int ldc,
    const float* __restrict__ bias, int bias_n)
{
  gemm_core(A, lda, B, K, OUTF32 ? Cf : nullptr, Cb, ldc, bias, bias_n,
            blockIdx.y * 128, blockIdx.x * 128);
}

// Two independent GEMMs in one launch.
__global__ __launch_bounds__(512) void gemm_bt_dual(
    const bf16* __restrict__ A0, int lda0, const bf16* __restrict__ B0, int K0,
    bf16* __restrict__ C0, int ldc0, int nbx0,
    const bf16* __restrict__ A1, int lda1, const bf16* __restrict__ B1, int K1,
    bf16* __restrict__ C1, int ldc1, int nbx1)
{
  int bid = blockIdx.x;
  if (bid < nbx0 * 16) {
    gemm_core(A0, lda0, B0, K0, nullptr, C0, ldc0, nullptr, 0,
              (bid / nbx0) * 128, (bid % nbx0) * 128);
  } else {
    bid -= nbx0 * 16;
    gemm_core(A1, lda1, B1, K1, nullptr, C1, ldc1, nullptr, 0,
              (bid / nbx1) * 128, (bid % nbx1) * 128);
  }
}

// ---------------------------------------------------------------- RoPE + V-transpose (fused)
__global__ void rope_tv(const bf16* __restrict__ QA, const bf16* __restrict__ c_all,
                        const float* __restrict__ cosb, const float* __restrict__ sinb,
                        bf16* __restrict__ Qr, bf16* __restrict__ Kr,
                        const bf16* __restrict__ KV, bf16* __restrict__ Vt)
{
  int bid = blockIdx.x;
  if (bid < 2048) {
    int t = bid;
    for (int idx = threadIdx.x; idx < 544; idx += 256) {
      if (idx < 512) {
        int h = idx >> 5, p = idx & 31;
        float x1 = (float)QA[(size_t)t * 3072 + 2048 + h * 64 + p];
        float x2 = (float)QA[(size_t)t * 3072 + 2048 + h * 64 + 32 + p];
        float c = cosb[t * 32 + p], s = sinb[t * 32 + p];
        Qr[(size_t)t * 1024 + h * 64 + p]      = (bf16)( x1 * c + x2 * s);
        Qr[(size_t)t * 1024 + h * 64 + 32 + p] = (bf16)(-x1 * s + x2 * c);
      } else {
        int p = idx - 512;
        float x1 = (float)c_all[(size_t)t * 2176 + 2048 + p];
        float x2 = (float)c_all[(size_t)t * 2176 + 2048 + 32 + p];
        float c = cosb[t * 32 + p], s = sinb[t * 32 + p];
        Kr[(size_t)t * 64 + p]      = (bf16)( x1 * c + x2 * s);
        Kr[(size_t)t * 64 + 32 + p] = (bf16)(-x1 * s + x2 * c);
      }
    }
  } else {
    __shared__ bf16 tile[32][33];
    int tb = bid - 2048;
    int t0 = (tb & 63) * 32, c0 = (tb >> 6) * 32;
    int tx = threadIdx.x & 31, ty = threadIdx.x >> 5;
#pragma unroll
    for (int r = 0; r < 4; ++r)
      tile[ty + r * 8][tx] = KV[(size_t)(t0 + ty + r * 8) * 4096 + 2048 + c0 + tx];
    __syncthreads();
#pragma unroll
    for (int r = 0; r < 4; ++r)
      Vt[(size_t)(c0 + ty + r * 8) * 2048 + t0 + tx] = tile[tx][ty + r * 8];
  }
}

// ---------------------------------------------------------------- flash attention
// LDS-staged K/Kr/V (double-buffered, XOR-swizzled, persistent pre-swizzled
// global pointers) + swapped-operand compute with lane-local stats,
// causal masks only near the diagonal, defer-max (THR=8).
__global__ __launch_bounds__(256) void attn_kernel(
    const bf16* __restrict__ QA,  // 2048 x 3072
    const bf16* __restrict__ Qr,  // 2048 x 1024
    const bf16* __restrict__ KV,  // 2048 x 4096 ([Kfull|Vfull])
    const bf16* __restrict__ Kr,  // 2048 x 64
    const bf16* __restrict__ Vt,  // 2048(c) x 2048(t)
    bf16* __restrict__ heads)     // 2048 x 2048
{
  __shared__ __align__(16) bf16 Kl[2][32 * 128];
  __shared__ __align__(16) bf16 Krl[2][32 * 64];
  __shared__ __align__(16) bf16 Vl[2][128 * 32];
  __shared__ __align__(16) bf16 Pl[4][16][40];

  const int tid = threadIdx.x;
  const int l = tid & 63;
  const int wid = tid >> 6;
  const int lr = l & 15, lg = l >> 4;

  // XCD clustering: 2 heads/XCD; halves in opposite qb order so co-resident
  // pairs (wg, wg+256) sum to a constant number of iterations.
  const int wg = blockIdx.x;
  const int xcd = wg & 7, inx = wg >> 3;
  const int half = inx >> 5, j = inx & 31;
  const int h = xcd * 2 + half;
  const int qb = half ? j : 31 - j;
  const int q0 = qb * 64 + wid * 16;
  const int q = q0 + lr;               // this lane's q-row

  const float scale = 0.041666666666666664f;  // 1/sqrt(576)
  f32x4 z = {0.f, 0.f, 0.f, 0.f};

  // persistent staging pointers (pre-swizzled source, rule #21)
  const int chK0 = tid, chK1 = tid + 256;
  const int rK0 = chK0 >> 4, pK0 = chK0 & 15;
  const int rK1 = chK1 >> 4, pK1 = chK1 & 15;
  const int cbK0 = (pK0 & 8) | ((pK0 & 7) ^ (rK0 & 7));
  const int cbK1 = (pK1 & 8) | ((pK1 & 7) ^ (rK1 & 7));
  const bf16* gK0 = &KV[(size_t)rK0 * 4096 + h * 128 + cbK0 * 8];
  const bf16* gK1 = &KV[(size_t)rK1 * 4096 + h * 128 + cbK1 * 8];
  const int rKr = tid >> 3, pKr = tid & 7, cbKr = pKr ^ (rKr & 7);
  const bf16* gKr = &Kr[(size_t)rKr * 64 + cbKr * 8];
  const int chV0 = tid, chV1 = tid + 256;
  const int rV0 = chV0 >> 2, pV0 = chV0 & 3, cbV0 = pV0 ^ ((rV0 >> 1) & 3);
  const int rV1 = chV1 >> 2, pV1 = chV1 & 3, cbV1 = pV1 ^ ((rV1 >> 1) & 3);
  const bf16* gV0 = &Vt[(size_t)(h * 128 + rV0) * 2048 + cbV0 * 8];
  const bf16* gV1 = &Vt[(size_t)(h * 128 + rV1) * 2048 + cbV1 * 8];
  bf16* dK0[2] = { &Kl[0][chK0 * 8], &Kl[1][chK0 * 8] };
  bf16* dK1[2] = { &Kl[0][chK1 * 8], &Kl[1][chK1 * 8] };
  bf16* dKr[2] = { &Krl[0][tid * 8], &Krl[1][tid * 8] };
  bf16* dV0[2] = { &Vl[0][chV0 * 8], &Vl[1][chV0 * 8] };
  bf16* dV1[2] = { &Vl[0][chV1 * 8], &Vl[1][chV1 * 8] };

  auto STAGE = [&](int b) {
    gload_lds16(gK0, b ? dK0[1] : dK0[0]);
    gload_lds16(gK1, b ? dK1[1] : dK1[0]);
    gload_lds16(gKr, b ? dKr[1] : dKr[0]);
    gload_lds16(gV0, b ? dV0[1] : dV0[0]);
    gload_lds16(gV1, b ? dV1[1] : dV1[0]);
    gK0 += 32 * 4096; gK1 += 32 * 4096; gKr += 32 * 64; gV0 += 32; gV1 += 32;
  };

  // Q B-fragments (col = q), d = 192 over 6 slices of 32 (registers)
  bf16x8 aq[6];
#pragma unroll
  for (int kc = 0; kc < 4; ++kc)
    aq[kc] = *(const bf16x8*)&QA[(size_t)q * 3072 + h * 128 + kc * 32 + lg * 8];
#pragma unroll
  for (int kc = 4; kc < 6; ++kc)
    aq[kc] = *(const bf16x8*)&Qr[(size_t)q * 1024 + h * 64 + (kc - 4) * 32 + lg * 8];

  float m_run = -1e30f, l_run = 0.f;
  f32x4 acc[8];
#pragma unroll
  for (int c = 0; c < 8; ++c) acc[c] = z;

  const int nIter = 2 * qb + 2;
  STAGE(0);
  __syncthreads();
  int cur = 0;
  for (int st = 0; st < nIter; ++st) {
    const int s0 = st * 32;
    if (st + 1 < nIter) STAGE(cur ^ 1);
    if (s0 <= q0 + 15) {                    // wave-uniform activity mask
      // QK^T (swapped): A = K rows from LDS, B = Q registers
      f32x4 sc[2];
      sc[0] = z; sc[1] = z;
#pragma unroll
      for (int t = 0; t < 2; ++t) {
        const int rr = t * 16 + lr;
#pragma unroll
        for (int kc = 0; kc < 4; ++kc) {
          int g = kc * 4 + lg;
          bf16x8 ka = *(const bf16x8*)&Kl[cur][rr * 128 + (((g & 8) | ((g & 7) ^ (rr & 7))) * 8)];
          sc[t] = mfma16(ka, aq[kc], sc[t]);
        }
#pragma unroll
        for (int kc = 4; kc < 6; ++kc) {
          int g = (kc - 4) * 4 + lg;
          bf16x8 ka = *(const bf16x8*)&Krl[cur][rr * 64 + ((g ^ (rr & 7)) * 8)];
          sc[t] = mfma16(ka, aq[kc], sc[t]);
        }
      }
      // lane holds S^T[k = s0 + t*16 + lg*4 + r][q]
      float pv[2][4];
      float mx = -1e30f;
      if (s0 + 31 > q0) {                   // near-diagonal: apply causal mask
#pragma unroll
        for (int t = 0; t < 2; ++t)
#pragma unroll
          for (int r = 0; r < 4; ++r) {
            int k = s0 + t * 16 + lg * 4 + r;
            float v = sc[t][r] * scale;
            if (k > q) v = -1e30f;
            pv[t][r] = v;
            mx = fmaxf(mx, v);
          }
      } else {
#pragma unroll
        for (int t = 0; t < 2; ++t)
#pragma unroll
          for (int r = 0; r < 4; ++r) {
            float v = sc[t][r] * scale;
            pv[t][r] = v;
            mx = fmaxf(mx, v);
          }
      }
      mx = fmaxf(mx, __shfl_xor(mx, 16, 64));
      mx = fmaxf(mx, __shfl_xor(mx, 32, 64));
      // defer-max (T13): only rescale when the max grew by > 8
      if (!__all(mx - m_run <= 8.f)) {
        float mnew = fmaxf(m_run, mx);
        float alpha = __expf(m_run - mnew);
        l_run *= alpha;
#pragma unroll
        for (int c = 0; c < 8; ++c)
#pragma unroll
          for (int r = 0; r < 4; ++r) acc[c][r] *= alpha;
        m_run = mnew;
      }
      float sum = 0.f;
#pragma unroll
      for (int t = 0; t < 2; ++t)
#pragma unroll
        for (int r = 0; r < 4; ++r) {
          float e = __expf(pv[t][r] - m_run);
          pv[t][r] = e;
          sum += e;
        }
      sum += __shfl_xor(sum, 16, 64);
      sum += __shfl_xor(sum, 32, 64);
      l_run += sum;
      // P^T -> per-wave LDS: Pl[q-local lr][k_local]
#pragma unroll
      for (int t = 0; t < 2; ++t)
#pragma unroll
        for (int hf = 0; hf < 2; ++hf) {
          bf16x2 w;
          w[0] = (bf16)pv[t][2 * hf];
          w[1] = (bf16)pv[t][2 * hf + 1];
          *(bf16x2*)&Pl[wid][lr][t * 16 + lg * 4 + 2 * hf] = w;
        }
      bf16x8 pa = *(const bf16x8*)&Pl[wid][lr][lg * 8];
      // PV (O^T): A = Vt rows from LDS, B = P^T
#pragma unroll
      for (int c = 0; c < 8; ++c) {
        int rv = c * 16 + lr;
        bf16x8 va = *(const bf16x8*)&Vl[cur][rv * 32 + ((lg ^ ((rv >> 1) & 3)) * 8)];
        acc[c] = mfma16(va, pa, acc[c]);
      }
    }
    __syncthreads();
    cur ^= 1;
  }

  const float inv = 1.f / l_run;
#pragma unroll
  for (int c = 0; c < 8; ++c) {
    bf16x4 o;
#pragma unroll
    for (int r = 0; r < 4; ++r) o[r] = (bf16)(acc[c][r] * inv);
    *(bf16x4*)&heads[(size_t)q * 2048 + h * 128 + c * 16 + lg * 4] = o;
  }
}

// ---------------------------------------------------------------- launch
extern "C" void kernel_launch(void* const* d_in, const int* in_sizes, int n_in,
                              void* d_out, int out_size, void* d_ws, size_t ws_size,
                              hipStream_t stream) {
  (void)in_sizes; (void)n_in; (void)out_size; (void)ws_size;
  const float* x      = (const float*)d_in[0];
  const float* cosp   = (const float*)d_in[1];
  const float* sinp   = (const float*)d_in[2];
  const float* Wq_d   = (const float*)d_in[3];
  const float* Wq_d_b = (const float*)d_in[4];
  const float* Wkv_d  = (const float*)d_in[5];
  const float* Wq_u   = (const float*)d_in[6];
  const float* Wk_u   = (const float*)d_in[7];
  const float* Wv_u   = (const float*)d_in[8];
  const float* W_qr   = (const float*)d_in[9];
  const float* W_kr   = (const float*)d_in[10];
  const float* W_out  = (const float*)d_in[11];

  char* ws = (char*)d_ws;
  size_t off = 0;
  auto alloc = [&](size_t bytes) {
    char* p = ws + off;
    off += (bytes + 255) & ~(size_t)255;
    return p;
  };
  bf16* xb    = (bf16*)alloc((size_t)2048 * 2048 * 2);  // reused as Vt after G1
  bf16* Wcat  = (bf16*)alloc((size_t)2176 * 2048 * 2);
  bf16* c_all = (bf16*)alloc((size_t)2048 * 2176 * 2);
  bf16* Wqu   = (bf16*)alloc((size_t)3072 * 1536 * 2);  // reused as heads
  bf16* QA    = (bf16*)alloc((size_t)2048 * 3072 * 2);
  bf16* Wkvu  = (bf16*)alloc((size_t)4096 * 512 * 2);
  bf16* KV    = (bf16*)alloc((size_t)2048 * 4096 * 2);
  bf16* Qr    = (bf16*)alloc((size_t)2048 * 1024 * 2);
  bf16* Kr    = (bf16*)alloc((size_t)2048 * 64 * 2);
  bf16* Wout  = (bf16*)alloc((size_t)2048 * 2048 * 2);
  bf16* Vt    = xb;
  bf16* heads = Wqu;

  CvtTable T;
  const float* srcs[9] = { x, Wq_d, Wkv_d, W_kr, Wq_u, W_qr, Wk_u, Wv_u, W_out };
  bf16* dsts[9] = { xb, Wcat, Wcat + (size_t)1536 * 2048, Wcat + (size_t)2048 * 2048,
                    Wqu, Wqu + (size_t)2048 * 1536, Wkvu, Wkvu + (size_t)2048 * 512, Wout };
  size_t ns[9] = { (size_t)2048 * 2048, (size_t)1536 * 2048, (size_t)512 * 2048,
                   (size_t)64 * 2048, (size_t)2048 * 1536, (size_t)1024 * 1536,
                   (size_t)2048 * 512, (size_t)2048 * 512, (size_t)2048 * 2048 };
  int cum = 0;
  for (int i = 0; i < 9; ++i) {
    T.s[i] = srcs[i]; T.d[i] = dsts[i]; T.cum[i] = cum;
    cum += (int)(ns[i] / 4);
  }
  T.cum[9] = cum;
  cvt_all<<<2048, 256, 0, stream>>>(T, cum);

  // G1: c_all = x @ [Wq_d;Wkv_d;W_kr]^T + bias(cols<1536)
  gemm_bt<false><<<dim3(17, 16), 512, 0, stream>>>(xb, 2048, Wcat, 2048,
                                                   nullptr, c_all, 2176, Wq_d_b, 1536);
  // G2 + G3 fused launch: QA = cq @ [Wq_u;W_qr]^T ; KV = ckv @ [Wk_u;Wv_u]^T
  gemm_bt_dual<<<24 * 16 + 32 * 16, 512, 0, stream>>>(
      c_all, 2176, Wqu, 1536, QA, 3072, 24,
      c_all + 1536, 2176, Wkvu, 512, KV, 4096, 32);
  // RoPE + V transpose fused
  rope_tv<<<2048 + 4096, 256, 0, stream>>>(QA, c_all, cosp, sinp, Qr, Kr, KV, Vt);
  attn_kernel<<<512, 256, 0, stream>>>(QA, Qr, KV, Kr, Vt, heads);
  // G4: out = heads @ W_out^T  (f32 to d_out)
  gemm_bt<true><<<dim3(16, 16), 512, 0, stream>>>(heads, 2048, Wout, 2048,
                                                  (float*)d_out, nullptr, 2048, nullptr, 0);
}